// Round 11
// baseline (36597.159 us; speedup 1.0000x reference)
//
#include <hip/hip_runtime.h>
#include <cstdint>

#define NROWS 10000
#define DIM   784
#define KP    800     // padded K (25 steps of 32)
#define CAND  150
#define MOUT  10
#define KMAX  64
#define TOT_W 117600  // DIM*CAND
#define TOT_B 150
#define NBLK2 313     // gemm blocks (32 rows each)
#define NTILE 625     // 16-row tiles (10000/16)
#define NKS   25      // K-steps of 32
#define NTB   40      // t-blocks (256 rows each)
#define GENB  460     // gen blocks riding in qr_tf
#define P1STRIDE 1664

typedef __attribute__((ext_vector_type(8))) short bf16x8;
typedef __attribute__((ext_vector_type(4))) float f32x4;

// ---------------- Threefry-2x32 (exact JAX partitionable semantics) ----------------
#define RND_(r) { x0 += x1; x1 = (x1 << r) | (x1 >> (32 - r)); x1 ^= x0; }

__device__ __host__ inline void threefry2x32(uint32_t k0, uint32_t k1,
                                             uint32_t c0, uint32_t c1,
                                             uint32_t* o0, uint32_t* o1) {
  uint32_t ks2 = 0x1BD11BDAu ^ k0 ^ k1;
  uint32_t x0 = c0 + k0, x1 = c1 + k1;
  RND_(13) RND_(15) RND_(26) RND_(6)
  x0 += k1;  x1 += ks2 + 1u;
  RND_(17) RND_(29) RND_(16) RND_(24)
  x0 += ks2; x1 += k0 + 2u;
  RND_(13) RND_(15) RND_(26) RND_(6)
  x0 += k0;  x1 += k1 + 3u;
  RND_(17) RND_(29) RND_(16) RND_(24)
  x0 += k1;  x1 += ks2 + 4u;
  RND_(13) RND_(15) RND_(26) RND_(6)
  x0 += ks2; x1 += k0 + 5u;
  *o0 = x0; *o1 = x1;
}

__device__ inline float uni01(uint32_t bits) {
  uint32_t fb = (bits >> 9) | 0x3F800000u;
  return __uint_as_float(fb) - 1.0f;
}

__device__ inline float scale_of(int j) {
  return (j < 50) ? 0.5f : ((j < 100) ? 1.0f : 5.0f);
}

// bf16 RNE helpers
__device__ inline uint16_t f2bf(float x) {
  uint32_t u = __float_as_uint(x);
  uint32_t r = u + 0x7FFFu + ((u >> 16) & 1u);
  return (uint16_t)(r >> 16);
}
__device__ inline float bf2f(uint16_t h) { return __uint_as_float(((uint32_t)h) << 16); }

// gen: thread g -> (c = g/784, kq = g%784); RNG counter f = kq*150 + c (JAX layout).
// Writes fp32 WrT[c][kq] and bf16x3 transposed splits WT*[c*KP + kq].
__device__ inline void gen_one2(int g, uint32_t kw0, uint32_t kw1, uint32_t kb0, uint32_t kb1,
                                float* __restrict__ WrT, uint16_t* __restrict__ WhiT,
                                uint16_t* __restrict__ Wlo1T, uint16_t* __restrict__ Wlo2T,
                                float* __restrict__ br) {
  if (g < TOT_W) {
    int c = g / 784, kq = g - c * 784;
    int f = kq * CAND + c;
    uint32_t o0, o1;
    threefry2x32(kw0, kw1, 0u, (uint32_t)f, &o0, &o1);
    float u = uni01(o0 ^ o1);
    float val = scale_of(c) * (2.0f * u - 1.0f);
    WrT[g] = val;                       // g == c*784 + kq
    uint16_t h0 = f2bf(val); float r1 = val - bf2f(h0);
    uint16_t h1 = f2bf(r1);  float r2 = r1 - bf2f(h1);
    uint16_t h2 = f2bf(r2);
    size_t o = (size_t)c * KP + kq;
    WhiT[o] = h0; Wlo1T[o] = h1; Wlo2T[o] = h2;
  } else if (g < TOT_W + TOT_B) {
    int gg = g - TOT_W;
    uint32_t o0, o1;
    threefry2x32(kb0, kb1, 0u, (uint32_t)gg, &o0, &o1);
    float u = uni01(o0 ^ o1);
    br[gg] = scale_of(gg) * (2.0f * u - 1.0f);
  }
}

__global__ __launch_bounds__(64) void init_kern(unsigned* __restrict__ counters) {
  if (threadIdx.x < 2) counters[threadIdx.x] = 0u;
}

// one-time: split X into 3 bf16 planes [row][KP], zero-padded k>=784
__global__ __launch_bounds__(256) void split_x_kern(const float* __restrict__ X,
                                                    uint16_t* __restrict__ Xhi,
                                                    uint16_t* __restrict__ Xlo1,
                                                    uint16_t* __restrict__ Xlo2) {
  size_t id = (size_t)blockIdx.x * 256 + threadIdx.x;
  if (id >= (size_t)NROWS * KP) return;
  int row = (int)(id / KP), kq = (int)(id - (size_t)row * KP);
  float x = (kq < DIM) ? X[(size_t)row * DIM + kq] : 0.f;
  uint16_t h0 = f2bf(x); float r1 = x - bf2f(h0);
  uint16_t h1 = f2bf(r1); float r2 = r1 - bf2f(h1);
  uint16_t h2 = f2bf(r2);
  Xhi[id] = h0; Xlo1[id] = h1; Xlo2[id] = h2;
}

// one-time: zero the 3 contiguous WT planes (pads must be 0)
__global__ __launch_bounds__(256) void zwt_kern(uint16_t* __restrict__ wt) {
  int id = blockIdx.x * 256 + threadIdx.x;
  if (id < 3 * 160 * KP) wt[id] = 0;
}

__global__ __launch_bounds__(256) void gen_rand_kern(float* __restrict__ WrT,
                                                     uint16_t* __restrict__ WhiT, uint16_t* __restrict__ Wlo1T,
                                                     uint16_t* __restrict__ Wlo2T, float* __restrict__ br,
                                                     uint32_t kw0, uint32_t kw1,
                                                     uint32_t kb0, uint32_t kb1) {
  int g = blockIdx.x * 256 + threadIdx.x;
  gen_one2(g, kw0, kw1, kb0, kb1, WrT, WhiT, Wlo1T, Wlo2T, br);
}

// ---------------- kernel A: MFMA bf16x3 GEMM + e-prologue + partials + last-block score/pick ----
// 313 blocks x 256 thr (4 waves). Wave w: row-tile rt = 2*b + (w>>1) (16 rows), cols (w&1)*80 .. +80.
__global__ __launch_bounds__(256) void gemm_mfma_kern(
    const uint16_t* __restrict__ Xhi, const uint16_t* __restrict__ Xlo1, const uint16_t* __restrict__ Xlo2,
    const float* __restrict__ Y, const float* __restrict__ Hm, const float* __restrict__ beta,
    const uint16_t* __restrict__ WhiT, const uint16_t* __restrict__ Wlo1T, const uint16_t* __restrict__ Wlo2T,
    const float* __restrict__ br_, const float* __restrict__ WrT,
    float* __restrict__ h_col, float* __restrict__ part1,
    float* __restrict__ outW, float* __restrict__ outb, int* __restrict__ ibest,
    unsigned* __restrict__ counter, int kprev, int k)
{
  __shared__ __align__(16) float red[2 * 1760];   // partials; reused as sums in tail
  __shared__ float et_s[32][MOUT];
  __shared__ float vbuf[160];
  __shared__ int lastFlag;
  __shared__ int sbest;

  int tid = threadIdx.x;
  int w = tid >> 6, L = tid & 63;
  int b = blockIdx.x;
  int rowblk = b * 32;

  // ---- prologue: et = Y - H*beta for block rows (serial-j chain, validated order) ----
  if (tid < 32) {
    int row = rowblk + tid;
    if (row < NROWS) {
      float s[10];
#pragma unroll
      for (int c = 0; c < 10; ++c) s[c] = 0.f;
      for (int j = 0; j <= kprev; ++j) {
        float hv = Hm[(size_t)j * NROWS + row];
#pragma unroll
        for (int c = 0; c < 10; ++c) s[c] = fmaf(hv, beta[j * 10 + c], s[c]);
      }
#pragma unroll
      for (int c = 0; c < 10; ++c) et_s[tid][c] = Y[(size_t)row * MOUT + c] - s[c];
    } else {
#pragma unroll
      for (int c = 0; c < 10; ++c) et_s[tid][c] = 0.f;
    }
  }

  int rt = b * 2 + (w >> 1);
  bool active = rt < NTILE;
  int r0 = rt * 16;
  int cg = (w & 1) * 80;
  int la = L & 15, lg = L >> 4;

  f32x4 acc[5];
#pragma unroll
  for (int ct = 0; ct < 5; ++ct) acc[ct] = (f32x4){0.f, 0.f, 0.f, 0.f};

  if (active) {
    size_t aoff = (size_t)(r0 + la) * KP + lg * 8;
    size_t bbase = (size_t)(cg + la) * KP + lg * 8;
    for (int ks = 0; ks < NKS; ++ks) {
      int kk = ks * 32;
      bf16x8 ahi  = *reinterpret_cast<const bf16x8*>(Xhi  + aoff + kk);
      bf16x8 alo1 = *reinterpret_cast<const bf16x8*>(Xlo1 + aoff + kk);
      bf16x8 alo2 = *reinterpret_cast<const bf16x8*>(Xlo2 + aoff + kk);
#pragma unroll
      for (int ct = 0; ct < 5; ++ct) {
        size_t bo = bbase + (size_t)ct * 16 * KP + kk;
        bf16x8 bhi  = *reinterpret_cast<const bf16x8*>(WhiT  + bo);
        bf16x8 blo1 = *reinterpret_cast<const bf16x8*>(Wlo1T + bo);
        bf16x8 blo2 = *reinterpret_cast<const bf16x8*>(Wlo2T + bo);
        acc[ct] = __builtin_amdgcn_mfma_f32_16x16x32_bf16(ahi,  blo2, acc[ct], 0, 0, 0);
        acc[ct] = __builtin_amdgcn_mfma_f32_16x16x32_bf16(alo2, bhi,  acc[ct], 0, 0, 0);
        acc[ct] = __builtin_amdgcn_mfma_f32_16x16x32_bf16(alo1, blo1, acc[ct], 0, 0, 0);
        acc[ct] = __builtin_amdgcn_mfma_f32_16x16x32_bf16(ahi,  blo1, acc[ct], 0, 0, 0);
        acc[ct] = __builtin_amdgcn_mfma_f32_16x16x32_bf16(alo1, bhi,  acc[ct], 0, 0, 0);
        acc[ct] = __builtin_amdgcn_mfma_f32_16x16x32_bf16(ahi,  bhi,  acc[ct], 0, 0, 0);
      }
    }
  }

  // zero red, then epilogue
  for (int i = tid; i < 2 * 1760; i += 256) red[i] = 0.f;
  __syncthreads();

  if (active) {
    int slot = w >> 1;
    int rl = slot * 16 + lg * 4;          // row within block
#pragma unroll
    for (int ct = 0; ct < 5; ++ct) {
      int col = cg + ct * 16 + la;
      float bb = (col < CAND) ? br_[col] : 0.f;
      float hv[4];
#pragma unroll
      for (int i = 0; i < 4; ++i)
        hv[i] = 1.0f / (1.0f + expf(-(acc[ct][i] + bb)));
      if (col < CAND) {
        float4 st = {hv[0], hv[1], hv[2], hv[3]};
        *(float4*)(h_col + (size_t)col * NROWS + r0 + lg * 4) = st;
      }
      float hh = 0.f, eth[10];
#pragma unroll
      for (int j = 0; j < 10; ++j) eth[j] = 0.f;
#pragma unroll
      for (int i = 0; i < 4; ++i) {
        hh = fmaf(hv[i], hv[i], hh);
#pragma unroll
        for (int j = 0; j < 10; ++j) eth[j] = fmaf(et_s[rl + i][j], hv[i], eth[j]);
      }
      hh += __shfl_xor(hh, 16); hh += __shfl_xor(hh, 32);
#pragma unroll
      for (int j = 0; j < 10; ++j) { eth[j] += __shfl_xor(eth[j], 16); eth[j] += __shfl_xor(eth[j], 32); }
      if (L < 16 && col < CAND) {
        float* d = red + slot * 1760 + col * 11;
        d[0] = hh;
#pragma unroll
        for (int j = 0; j < 10; ++j) d[1 + j] = eth[j];
      }
    }
  }
  __syncthreads();
  for (int idx = tid; idx < CAND * 11; idx += 256)
    part1[(size_t)b * P1STRIDE + idx] = red[idx] + red[1760 + idx];

  // ---- global last-done: reduce part1, v, argmax, record ----
  __syncthreads();
  if (tid == 0) {
    __threadfence();
    unsigned d = __hip_atomic_fetch_add(counter, 1u, __ATOMIC_ACQ_REL, __HIP_MEMORY_SCOPE_AGENT);
    lastFlag = (d == NBLK2 - 1) ? 1 : 0;
  }
  __syncthreads();
  if (!lastFlag) return;
  if (tid == 0) { __threadfence(); *counter = 0u; }

  float acc7[7];
#pragma unroll
  for (int ii = 0; ii < 7; ++ii) acc7[ii] = 0.f;
  for (int b2 = 0; b2 < NBLK2; ++b2) {
    const float* p = part1 + (size_t)b2 * P1STRIDE;
#pragma unroll
    for (int ii = 0; ii < 7; ++ii) {
      int idx = tid + ii * 256;
      if (idx < CAND * 11) acc7[ii] += p[idx];
    }
  }
#pragma unroll
  for (int ii = 0; ii < 7; ++ii) {
    int idx = tid + ii * 256;
    if (idx < CAND * 11) red[idx] = acc7[ii];
  }
  __syncthreads();
  if (tid < CAND) {
    float hh = red[tid * 11];
    float accv = 0.f;
#pragma unroll
    for (int c = 0; c < 10; ++c) { float d = red[tid * 11 + 1 + c]; accv += (d * d) / hh; }
    vbuf[tid] = accv / 10.0f;
  }
  __syncthreads();
  if (tid == 0) {
    float bv = vbuf[0]; int bi = 0;
    for (int c = 1; c < CAND; ++c) {
      float v = vbuf[c];
      if (v > bv) { bv = v; bi = c; }
    }
    sbest = bi; *ibest = bi; outb[k] = br_[bi];
  }
  __syncthreads();
  int best = sbest;
  for (int i = tid; i < DIM; i += 256) outW[(size_t)i * KMAX + k] = WrT[(size_t)best * DIM + i];
}

// ---------------- kernel B: r1[j] = (t_j . h_c)/r2[j]; block k copies H col ----
__global__ __launch_bounds__(256) void qr_r1_kern(const float* __restrict__ h_col, float* __restrict__ Hm,
                                                  const float* __restrict__ Qm, const float* __restrict__ r2g,
                                                  float* __restrict__ r1g, const int* __restrict__ ibest, int k) {
  int j = blockIdx.x, tid = threadIdx.x;
  int best = *ibest;
  const float* hc = h_col + (size_t)best * NROWS;
  if (j == k) {
    for (int i = tid; i < NROWS; i += 256)
      Hm[(size_t)k * NROWS + i] = hc[i];
    return;
  }
  const float* tj = Qm + (size_t)j * NROWS;
  float local = 0.f;
#pragma unroll 4
  for (int i = tid; i < NROWS; i += 256)
    local = fmaf(tj[i], hc[i], local);
  local += __shfl_xor(local, 32); local += __shfl_xor(local, 16);
  local += __shfl_xor(local, 8);  local += __shfl_xor(local, 4);
  local += __shfl_xor(local, 2);  local += __shfl_xor(local, 1);
  __shared__ float wred[4];
  int wid = tid >> 6, lane = tid & 63;
  if (lane == 0) wred[wid] = local;
  __syncthreads();
  if (tid == 0) {
    float s = wred[0] + wred[1] + wred[2] + wred[3];
    r1g[j] = s / r2g[j];
  }
}

// ---------------- kernel C: t + partials + last-block finalize; gen blocks ride along ----------------
__global__ __launch_bounds__(256) void qr_tf_kern(
    const float* __restrict__ h_col, const float* __restrict__ Y,
    const float* __restrict__ Hm, float* __restrict__ Qm,
    float* __restrict__ r2g, const float* __restrict__ r1g,
    float* __restrict__ Rm, float* __restrict__ QT, float* __restrict__ scal,
    float* __restrict__ outBeta, float* __restrict__ part2,
    const int* __restrict__ ibest, unsigned* __restrict__ counter,
    float* __restrict__ WrT, uint16_t* __restrict__ WhiT, uint16_t* __restrict__ Wlo1T,
    uint16_t* __restrict__ Wlo2T, float* __restrict__ br,
    uint32_t kw0, uint32_t kw1, uint32_t kb0, uint32_t kb1, int k) {
  int b = blockIdx.x, tid = threadIdx.x;
  if (b >= NTB) {
    int g = (b - NTB) * 256 + tid;
    gen_one2(g, kw0, kw1, kb0, kb1, WrT, WhiT, Wlo1T, Wlo2T, br);
    return;
  }

  __shared__ float r1s[KMAX];
  __shared__ float coef[KMAX];
  __shared__ float wred[4][23];
  __shared__ int lastFlag;
  if (tid < k) {
    float r1v = r1g[tid];
    r1s[tid] = r1v;
    coef[tid] = r1v / r2g[tid];
  }
  __syncthreads();

  int best = *ibest;
  const float* hc_g = h_col + (size_t)best * NROWS;
  int i = b * 256 + tid;
  float tval = 0.f, hc = 0.f, h0 = 0.f;
  float yv[10];
#pragma unroll
  for (int c = 0; c < 10; ++c) yv[c] = 0.f;
  if (i < NROWS) {
    hc = hc_g[i];
    float s0 = 0.f, s1 = 0.f, s2 = 0.f, s3 = 0.f;
    int jj = 0;
    for (; jj + 3 < k; jj += 4) {
      s0 = fmaf(Qm[(size_t)jj * NROWS + i],       coef[jj],     s0);
      s1 = fmaf(Qm[(size_t)(jj + 1) * NROWS + i], coef[jj + 1], s1);
      s2 = fmaf(Qm[(size_t)(jj + 2) * NROWS + i], coef[jj + 2], s2);
      s3 = fmaf(Qm[(size_t)(jj + 3) * NROWS + i], coef[jj + 3], s3);
    }
    for (; jj < k; ++jj) s0 = fmaf(Qm[(size_t)jj * NROWS + i], coef[jj], s0);
    float s = (s0 + s1) + (s2 + s3);
    tval = hc - s;
    Qm[(size_t)k * NROWS + i] = tval;
#pragma unroll
    for (int c = 0; c < 10; ++c) yv[c] = Y[(size_t)i * MOUT + c];
    if (k == 1) h0 = Hm[i];
  }

  int np = (k == 1) ? 23 : 11;
  float p[23];
  p[0] = tval * tval;
#pragma unroll
  for (int c = 0; c < 10; ++c) p[1 + c] = tval * yv[c];
  if (k == 1) {
    p[11] = hc * hc;
    p[12] = h0 * hc;
#pragma unroll
    for (int c = 0; c < 10; ++c) p[13 + c] = hc * yv[c];
  }
  int wid = tid >> 6, lane = tid & 63;
  for (int c = 0; c < np; ++c) {
    float v = p[c];
    v += __shfl_xor(v, 32); v += __shfl_xor(v, 16); v += __shfl_xor(v, 8);
    v += __shfl_xor(v, 4);  v += __shfl_xor(v, 2);  v += __shfl_xor(v, 1);
    if (lane == 0) wred[wid][c] = v;
  }
  __syncthreads();
  if (tid < np) part2[b * 23 + tid] = wred[0][tid] + wred[1][tid] + wred[2][tid] + wred[3][tid];

  // ---- last-done block: finalize ----
  __syncthreads();
  if (tid == 0) {
    __threadfence();
    unsigned d = __hip_atomic_fetch_add(counter, 1u, __ATOMIC_ACQ_REL, __HIP_MEMORY_SCOPE_AGENT);
    lastFlag = (d == NTB - 1) ? 1 : 0;
  }
  __syncthreads();
  if (!lastFlag) return;
  if (tid == 0) { __threadfence(); *counter = 0u; }

  __shared__ float vals[23];
  __shared__ float bsh[KMAX * 10];
  if (tid < np) {
    float s = 0.f;
    for (int b2 = 0; b2 < NTB; ++b2) s += part2[b2 * 23 + tid];
    vals[tid] = s;
  }
  __syncthreads();
  float r2 = sqrtf(vals[0]);
  if (tid < k) Rm[tid * KMAX + k] = r1s[tid];
  if (tid == 0) { Rm[k * KMAX + k] = r2; r2g[k] = r2; }
  if (tid < 10) QT[k * 10 + tid] = vals[1 + tid] / r2;
  if (k == 0 && tid < 11) scal[1 + tid] = vals[tid];
  __syncthreads();
  if (k == 0) {
    if (tid < 10) outBeta[tid] = (1.0f / vals[0]) * vals[1 + tid];
  } else if (k == 1) {
    if (tid < 10) {
      float g00 = scal[1], g0y = scal[2 + tid];
      float s11 = vals[11], s01 = vals[12], s1y = vals[13 + tid];
      float det = g00 * s11 - s01 * s01;
      float i00 = s11 / det, i01 = -s01 / det, i11 = g00 / det;
      outBeta[tid]      = i00 * g0y + i01 * s1y;
      outBeta[10 + tid] = i01 * g0y + i11 * s1y;
    }
  } else {
    if (tid < 10) {
      for (int row = k; row >= 0; --row) {
        float s = QT[row * 10 + tid];
        for (int jj = row + 1; jj <= k; ++jj) s = fmaf(-Rm[row * KMAX + jj], bsh[jj * 10 + tid], s);
        float bv = s / Rm[row * KMAX + row];
        bsh[row * 10 + tid] = bv;
        outBeta[row * 10 + tid] = bv;
      }
    }
  }
}

// ---------------- host ----------------
extern "C" void kernel_launch(void* const* d_in, const int* in_sizes, int n_in,
                              void* d_out, int out_size, void* d_ws, size_t ws_size,
                              hipStream_t stream) {
  const float* X = (const float*)d_in[0];
  const float* Y = (const float*)d_in[1];
  float* out = (float*)d_out;
  float* outW    = out;
  float* outb    = out + (size_t)DIM * KMAX;
  float* outBeta = outb + KMAX;

  float* ws = (float*)d_ws;
  size_t off = 0;
  float* h_col = ws + off; off += (size_t)NROWS * CAND;
  float* WrT   = ws + off; off += TOT_W;
  float* br    = ws + off; off += 256;
  float* Hm    = ws + off; off += (size_t)KMAX * NROWS;
  float* Qm    = ws + off; off += (size_t)KMAX * NROWS;
  float* Rm    = ws + off; off += (size_t)KMAX * KMAX;
  float* QT    = ws + off; off += (size_t)KMAX * MOUT;
  float* r2g   = ws + off; off += KMAX;
  float* r1g   = ws + off; off += KMAX;
  float* part1 = ws + off; off += (size_t)NBLK2 * P1STRIDE;
  float* part2 = ws + off; off += (size_t)NTB * 23 + 8;
  float* scal  = ws + off; off += 16;
  int*   ibest = (int*)(ws + off); off += 4;
  unsigned* counters = (unsigned*)(ws + off); off += 8;   // [0]=gemm, [1]=qr_tf
  uint16_t* Xhi  = (uint16_t*)(ws + off); off += (size_t)NROWS * KP / 2;
  uint16_t* Xlo1 = (uint16_t*)(ws + off); off += (size_t)NROWS * KP / 2;
  uint16_t* Xlo2 = (uint16_t*)(ws + off); off += (size_t)NROWS * KP / 2;
  uint16_t* WTbase = (uint16_t*)(ws + off); off += (size_t)3 * 160 * KP / 2;
  uint16_t* WhiT  = WTbase;
  uint16_t* Wlo1T = WTbase + 160 * KP;
  uint16_t* Wlo2T = WTbase + 2 * 160 * KP;

  // precompute key chain on host (bit-exact JAX split semantics)
  uint32_t kws0[KMAX], kws1[KMAX], kbs0[KMAX], kbs1[KMAX];
  uint32_t key0 = 0u, key1 = 42u;
  for (int k = 0; k < KMAX; ++k) {
    uint32_t o0[3], o1[3];
    for (int t = 0; t < 3; ++t)
      threefry2x32(key0, key1, 0u, (uint32_t)t, &o0[t], &o1[t]);
    kws0[k] = o0[1]; kws1[k] = o1[1]; kbs0[k] = o0[2]; kbs1[k] = o1[2];
    key0 = o0[0]; key1 = o1[0];
  }

  init_kern<<<1, 64, 0, stream>>>(counters);
  split_x_kern<<<(int)(((size_t)NROWS * KP + 255) / 256), 256, 0, stream>>>(X, Xhi, Xlo1, Xlo2);
  zwt_kern<<<(3 * 160 * KP + 255) / 256, 256, 0, stream>>>(WTbase);
  gen_rand_kern<<<GENB, 256, 0, stream>>>(WrT, WhiT, Wlo1T, Wlo2T, br,
                                          kws0[0], kws1[0], kbs0[0], kbs1[0]);

  for (int k = 0; k < KMAX; ++k) {
    gemm_mfma_kern<<<NBLK2, 256, 0, stream>>>(Xhi, Xlo1, Xlo2, Y, Hm, outBeta,
                                              WhiT, Wlo1T, Wlo2T, br, WrT,
                                              h_col, part1, outW, outb, ibest,
                                              &counters[0], k - 1, k);
    qr_r1_kern<<<k + 1, 256, 0, stream>>>(h_col, Hm, Qm, r2g, r1g, ibest, k);
    bool genNext = (k + 1 < KMAX);
    int nb = genNext ? (NTB + GENB) : NTB;
    int kn = genNext ? (k + 1) : 0;
    qr_tf_kern<<<nb, 256, 0, stream>>>(h_col, Y, Hm, Qm, r2g, r1g, Rm, QT, scal,
                                       outBeta, part2, ibest, &counters[1],
                                       WrT, WhiT, Wlo1T, Wlo2T, br,
                                       kws0[kn], kws1[kn], kbs0[kn], kbs1[kn], k);
  }
}